// Round 4
// baseline (863.548 us; speedup 1.0000x reference)
//
#include <hip/hip_runtime.h>

#define N_TOT      150000
#define N_USER     50000
#define N_EDGE     2400000
#define DIM        64
#define OUT_STRIDE 256
#define SLOPE      0.2f
#define NB_SCAN    ((N_TOT + 255) / 256)   // 587

// ---- ws layout ----
// ego    : [N,64] fp32 (in-place across layers)
// side   : [N,64] fp32   (aliased as rank[E] during CSR build)
// epack  : [E] int2 (col, val_bits)
// row_ptr: [N+1] int
// cnt    : [N] int (histogram counts)
// bsum   : [NB_SCAN] int

__global__ void init_ego(const float* __restrict__ ue, const float* __restrict__ ie,
                         float* __restrict__ ego, float* __restrict__ out) {
    int idx = blockIdx.x * blockDim.x + threadIdx.x;          // float4 index
    if (idx >= N_TOT * DIM / 4) return;
    int n  = idx >> 4;
    int c4 = idx & 15;
    float4 v = (n < N_USER) ? ((const float4*)ue)[idx]
                            : ((const float4*)ie)[idx - N_USER * (DIM / 4)];
    ((float4*)ego)[idx] = v;
    ((float4*)out)[n * (OUT_STRIDE / 4) + c4] = v;
}

// Histogram + per-edge rank in ONE pass: the atomic return value IS the rank.
// 4 edges per thread (int4 reads). Measured stable at ~100 us; ILP changes
// don't move it (atomic line-ownership bound).
__global__ void hist_rank(const int* __restrict__ rows, int* __restrict__ cnt,
                          int* __restrict__ rank) {
    int t = blockIdx.x * blockDim.x + threadIdx.x;
    if (t >= N_EDGE / 4) return;
    int4 r4 = ((const int4*)rows)[t];
    int4 k4;
    k4.x = atomicAdd(&cnt[r4.x], 1);
    k4.y = atomicAdd(&cnt[r4.y], 1);
    k4.z = atomicAdd(&cnt[r4.z], 1);
    k4.w = atomicAdd(&cnt[r4.w], 1);
    ((int4*)rank)[t] = k4;
}

// Hierarchical scan, stage 1: per-256-chunk exclusive scan + block totals.
__global__ __launch_bounds__(256) void scan_partial(const int* __restrict__ cnt,
                                                    int* __restrict__ row_ptr,
                                                    int* __restrict__ bsum) {
    __shared__ int s[256];
    int tid = threadIdx.x;
    int i = blockIdx.x * 256 + tid;
    int v = (i < N_TOT) ? cnt[i] : 0;
    s[tid] = v;
    __syncthreads();
    for (int off = 1; off < 256; off <<= 1) {                 // Hillis-Steele inclusive
        int t = (tid >= off) ? s[tid - off] : 0;
        __syncthreads();
        s[tid] += t;
        __syncthreads();
    }
    if (i < N_TOT) row_ptr[i] = s[tid] - v;                   // local exclusive
    if (tid == 255) bsum[blockIdx.x] = s[255];
}

// Stage 2: single block scans the NB_SCAN block totals (exclusive, in place).
__global__ __launch_bounds__(1024) void scan_bsums(int* __restrict__ bsum) {
    __shared__ int s[1024];
    int tid = threadIdx.x;
    int v = (tid < NB_SCAN) ? bsum[tid] : 0;
    s[tid] = v;
    __syncthreads();
    for (int off = 1; off < 1024; off <<= 1) {
        int t = (tid >= off) ? s[tid - off] : 0;
        __syncthreads();
        s[tid] += t;
        __syncthreads();
    }
    if (tid < NB_SCAN) bsum[tid] = s[tid] - v;
}

// Stage 3: add block offsets; write final row_ptr.
__global__ __launch_bounds__(256) void add_offsets(int* __restrict__ row_ptr,
                                                   const int* __restrict__ bsum) {
    int i = blockIdx.x * 256 + threadIdx.x;
    if (i < N_TOT) row_ptr[i] += bsum[blockIdx.x];
    if (i == 0) row_ptr[N_TOT] = N_EDGE;
}

// Atomic-free scatter: pos = row_ptr[row] + rank (deterministic). Pure
// streaming reads + one random 8B write per edge. 4 edges/thread for MLP.
__global__ void scatter_edges(const int* __restrict__ rows, const int* __restrict__ cols,
                              const float* __restrict__ vals,
                              const int* __restrict__ row_ptr,
                              const int* __restrict__ rank, int2* __restrict__ epack) {
    int t = blockIdx.x * blockDim.x + threadIdx.x;
    if (t >= N_EDGE / 4) return;
    int4   r4 = ((const int4*)rows)[t];
    int4   k4 = ((const int4*)rank)[t];
    int4   c4 = ((const int4*)cols)[t];
    float4 v4 = ((const float4*)vals)[t];
    epack[row_ptr[r4.x] + k4.x] = make_int2(c4.x, __float_as_int(v4.x));
    epack[row_ptr[r4.y] + k4.y] = make_int2(c4.y, __float_as_int(v4.y));
    epack[row_ptr[r4.z] + k4.z] = make_int2(c4.z, __float_as_int(v4.z));
    epack[row_ptr[r4.w] + k4.w] = make_int2(c4.w, __float_as_int(v4.w));
}

// side = A @ ego (CSR gather). One wave per row; 4 edge-groups x 16 lanes,
// float4 per lane. 32-edge head: 4 independent epack loads -> 8 gathers
// (8 KB/wave) in flight. Per-group edge order identical to the 8-edge loop,
// so summation is bitwise-identical.
__global__ __launch_bounds__(256) void spmm_gather(
    const int* __restrict__ row_ptr, const int2* __restrict__ epack,
    const float* __restrict__ ego, float* __restrict__ side) {
    int lane = threadIdx.x & 63;
    int row  = blockIdx.x * 4 + (threadIdx.x >> 6);
    if (row >= N_TOT) return;
    int beg = row_ptr[row];
    int end = row_ptr[row + 1];
    int g = lane >> 4;          // edge sub-group 0..3
    int q = lane & 15;          // dim quarter: dims q*4 .. q*4+3
    float4 acc = make_float4(0.f, 0.f, 0.f, 0.f);
    int i = beg;
    for (; i + 32 <= end; i += 32) {
        int4 e0 = ((const int4*)(epack + i))[g];
        int4 e1 = ((const int4*)(epack + i + 8))[g];
        int4 e2 = ((const int4*)(epack + i + 16))[g];
        int4 e3 = ((const int4*)(epack + i + 24))[g];
        float4 va = ((const float4*)(ego + (size_t)e0.x * DIM))[q];
        float4 vb = ((const float4*)(ego + (size_t)e0.z * DIM))[q];
        float4 vc = ((const float4*)(ego + (size_t)e1.x * DIM))[q];
        float4 vd = ((const float4*)(ego + (size_t)e1.z * DIM))[q];
        float4 ve = ((const float4*)(ego + (size_t)e2.x * DIM))[q];
        float4 vf = ((const float4*)(ego + (size_t)e2.z * DIM))[q];
        float4 vg = ((const float4*)(ego + (size_t)e3.x * DIM))[q];
        float4 vh = ((const float4*)(ego + (size_t)e3.z * DIM))[q];
        float wa = __int_as_float(e0.y), wb = __int_as_float(e0.w);
        float wc = __int_as_float(e1.y), wd = __int_as_float(e1.w);
        float we = __int_as_float(e2.y), wf = __int_as_float(e2.w);
        float wg = __int_as_float(e3.y), wh = __int_as_float(e3.w);
        acc.x = fmaf(wa, va.x, acc.x); acc.y = fmaf(wa, va.y, acc.y);
        acc.z = fmaf(wa, va.z, acc.z); acc.w = fmaf(wa, va.w, acc.w);
        acc.x = fmaf(wb, vb.x, acc.x); acc.y = fmaf(wb, vb.y, acc.y);
        acc.z = fmaf(wb, vb.z, acc.z); acc.w = fmaf(wb, vb.w, acc.w);
        acc.x = fmaf(wc, vc.x, acc.x); acc.y = fmaf(wc, vc.y, acc.y);
        acc.z = fmaf(wc, vc.z, acc.z); acc.w = fmaf(wc, vc.w, acc.w);
        acc.x = fmaf(wd, vd.x, acc.x); acc.y = fmaf(wd, vd.y, acc.y);
        acc.z = fmaf(wd, vd.z, acc.z); acc.w = fmaf(wd, vd.w, acc.w);
        acc.x = fmaf(we, ve.x, acc.x); acc.y = fmaf(we, ve.y, acc.y);
        acc.z = fmaf(we, ve.z, acc.z); acc.w = fmaf(we, ve.w, acc.w);
        acc.x = fmaf(wf, vf.x, acc.x); acc.y = fmaf(wf, vf.y, acc.y);
        acc.z = fmaf(wf, vf.z, acc.z); acc.w = fmaf(wf, vf.w, acc.w);
        acc.x = fmaf(wg, vg.x, acc.x); acc.y = fmaf(wg, vg.y, acc.y);
        acc.z = fmaf(wg, vg.z, acc.z); acc.w = fmaf(wg, vg.w, acc.w);
        acc.x = fmaf(wh, vh.x, acc.x); acc.y = fmaf(wh, vh.y, acc.y);
        acc.z = fmaf(wh, vh.z, acc.z); acc.w = fmaf(wh, vh.w, acc.w);
    }
    for (; i + 8 <= end; i += 8) {
        int4 ee = ((const int4*)(epack + i))[g];
        float4 va = ((const float4*)(ego + (size_t)ee.x * DIM))[q];
        float4 vb = ((const float4*)(ego + (size_t)ee.z * DIM))[q];
        float wa = __int_as_float(ee.y);
        float wb = __int_as_float(ee.w);
        acc.x = fmaf(wa, va.x, acc.x); acc.y = fmaf(wa, va.y, acc.y);
        acc.z = fmaf(wa, va.z, acc.z); acc.w = fmaf(wa, va.w, acc.w);
        acc.x = fmaf(wb, vb.x, acc.x); acc.y = fmaf(wb, vb.y, acc.y);
        acc.z = fmaf(wb, vb.z, acc.z); acc.w = fmaf(wb, vb.w, acc.w);
    }
    for (; i < end; i += 4) {                                 // tail: <=7 edges
        if (i + g < end) {
            int2 e = epack[i + g];
            float4 v = ((const float4*)(ego + (size_t)e.x * DIM))[q];
            float w = __int_as_float(e.y);
            acc.x = fmaf(w, v.x, acc.x); acc.y = fmaf(w, v.y, acc.y);
            acc.z = fmaf(w, v.z, acc.z); acc.w = fmaf(w, v.w, acc.w);
        }
    }
    // combine the 4 edge-groups (lane bits 4 and 5)
    acc.x += __shfl_xor(acc.x, 16, 64); acc.y += __shfl_xor(acc.y, 16, 64);
    acc.z += __shfl_xor(acc.z, 16, 64); acc.w += __shfl_xor(acc.w, 16, 64);
    acc.x += __shfl_xor(acc.x, 32, 64); acc.y += __shfl_xor(acc.y, 32, 64);
    acc.z += __shfl_xor(acc.z, 32, 64); acc.w += __shfl_xor(acc.w, 32, 64);
    if (g == 0)
        *(float4*)(side + (size_t)row * DIM + q * 4) = acc;
}

// Dual 64x64 GEMM + LeakyReLU + add + l2norm per 64-row tile.
// NO side/p transpose staging: each thread reads its 4 rows of side/ego
// directly as row-major float4 (L1-broadcast across the 16 tx lanes;
// 32 KB tile -> L1-resident). Only W matrices live in LDS. k ascending
// per (i,j) accumulator -> bitwise-identical to the staged version.
__global__ __launch_bounds__(256) void transform_gemm(
    const float* __restrict__ Wg, const float* __restrict__ bgv,
    const float* __restrict__ Wb, const float* __restrict__ bbv,
    const float* __restrict__ side, float* __restrict__ ego,
    float* __restrict__ out, int layer) {
    __shared__ float sWg[DIM][DIM];    // sWg[k][c]
    __shared__ float sWb[DIM][DIM];
    int tid = threadIdx.x;
    int R0  = blockIdx.x * 64;

    #pragma unroll
    for (int it = 0; it < 4; ++it) {                          // stage W matrices
        int f = tid + it * 256;                               // float4 idx 0..1023
        float4 wg = ((const float4*)Wg)[f];
        float4 wb = ((const float4*)Wb)[f];
        int k = f >> 4, c = (f & 15) * 4;
        *(float4*)&sWg[k][c] = wg;
        *(float4*)&sWb[k][c] = wb;
    }
    __syncthreads();

    int tx = tid & 15, ty = tid >> 4;
    int c0 = tx * 4, r0 = ty * 4;
    int rowbase = R0 + r0;
    float ag[4][4] = {{0.f}}, ab[4][4] = {{0.f}};

    for (int k0 = 0; k0 < DIM; k0 += 4) {
        float sreg[4][4], preg[4][4];                         // constant-indexed -> regs
        #pragma unroll
        for (int i = 0; i < 4; ++i) {
            int row = rowbase + i;
            float4 sv = make_float4(0.f, 0.f, 0.f, 0.f);
            float4 ev = make_float4(0.f, 0.f, 0.f, 0.f);
            if (row < N_TOT) {
                sv = *(const float4*)&side[(size_t)row * DIM + k0];
                ev = *(const float4*)&ego [(size_t)row * DIM + k0];
            }
            sreg[i][0] = sv.x; sreg[i][1] = sv.y; sreg[i][2] = sv.z; sreg[i][3] = sv.w;
            preg[i][0] = sv.x * ev.x; preg[i][1] = sv.y * ev.y;
            preg[i][2] = sv.z * ev.z; preg[i][3] = sv.w * ev.w;
        }
        #pragma unroll
        for (int kk = 0; kk < 4; ++kk) {
            float4 g4 = *(const float4*)&sWg[k0 + kk][c0];
            float4 b4 = *(const float4*)&sWb[k0 + kk][c0];
            float gg[4] = {g4.x, g4.y, g4.z, g4.w};
            float bw[4] = {b4.x, b4.y, b4.z, b4.w};
            #pragma unroll
            for (int i = 0; i < 4; ++i) {
                float ss = sreg[i][kk];
                float pp = preg[i][kk];
                #pragma unroll
                for (int j = 0; j < 4; ++j) {
                    ag[i][j] = fmaf(ss, gg[j], ag[i][j]);
                    ab[i][j] = fmaf(pp, bw[j], ab[i][j]);
                }
            }
        }
    }

    float4 bg4 = *(const float4*)&bgv[c0];
    float4 bb4 = *(const float4*)&bbv[c0];
    float bgl[4] = {bg4.x, bg4.y, bg4.z, bg4.w};
    float bbl[4] = {bb4.x, bb4.y, bb4.z, bb4.w};

    float ne[4][4];
    float ss2[4];
    #pragma unroll
    for (int i = 0; i < 4; ++i) {
        float s = 0.f;
        #pragma unroll
        for (int j = 0; j < 4; ++j) {
            float g = ag[i][j] + bgl[j];
            float b = ab[i][j] + bbl[j];
            g = g > 0.f ? g : SLOPE * g;
            b = b > 0.f ? b : SLOPE * b;
            float v = g + b;
            ne[i][j] = v;
            s = fmaf(v, v, s);
        }
        ss2[i] = s;
    }
    #pragma unroll
    for (int m = 1; m < 16; m <<= 1) {                        // reduce across tx group
        #pragma unroll
        for (int i = 0; i < 4; ++i) ss2[i] += __shfl_xor(ss2[i], m, 64);
    }

    float* outbase = out + (size_t)(layer + 1) * DIM;
    #pragma unroll
    for (int i = 0; i < 4; ++i) {
        int row = rowbase + i;
        if (row >= N_TOT) break;
        float inv = 1.f / fmaxf(sqrtf(ss2[i]), 1e-12f);
        float4 e4 = make_float4(ne[i][0], ne[i][1], ne[i][2], ne[i][3]);
        float4 o4 = make_float4(ne[i][0] * inv, ne[i][1] * inv, ne[i][2] * inv, ne[i][3] * inv);
        *(float4*)&ego[(size_t)row * DIM + c0] = e4;
        *(float4*)&outbase[(size_t)row * OUT_STRIDE + c0] = o4;
    }
}

extern "C" void kernel_launch(void* const* d_in, const int* in_sizes, int n_in,
                              void* d_out, int out_size, void* d_ws, size_t ws_size,
                              hipStream_t stream) {
    const float* ue = (const float*)d_in[0];
    const float* ie = (const float*)d_in[1];
    const float* Wg[3] = {(const float*)d_in[2], (const float*)d_in[6], (const float*)d_in[10]};
    const float* bg[3] = {(const float*)d_in[3], (const float*)d_in[7], (const float*)d_in[11]};
    const float* Wb[3] = {(const float*)d_in[4], (const float*)d_in[8], (const float*)d_in[12]};
    const float* bb[3] = {(const float*)d_in[5], (const float*)d_in[9], (const float*)d_in[13]};
    const float* vals = (const float*)d_in[14];
    const int*  rows  = (const int*)d_in[15];
    const int*  cols  = (const int*)d_in[16];
    float* out = (float*)d_out;

    float* ego     = (float*)d_ws;
    float* side    = ego + (size_t)N_TOT * DIM;
    int2*  epack   = (int2*)(side + (size_t)N_TOT * DIM);
    int*   row_ptr = (int*)(epack + N_EDGE);
    int*   cnt     = row_ptr + (N_TOT + 16);
    int*   bsum    = cnt + N_TOT;
    int*   rank    = (int*)side;      // alias: side unused until layer loop

    // CSR build (adj constant across layers)
    hipMemsetAsync(cnt, 0, (size_t)N_TOT * sizeof(int), stream);
    hist_rank<<<(N_EDGE / 4 + 255) / 256, 256, 0, stream>>>(rows, cnt, rank);
    scan_partial<<<NB_SCAN, 256, 0, stream>>>(cnt, row_ptr, bsum);
    scan_bsums<<<1, 1024, 0, stream>>>(bsum);
    add_offsets<<<NB_SCAN, 256, 0, stream>>>(row_ptr, bsum);
    scatter_edges<<<(N_EDGE / 4 + 255) / 256, 256, 0, stream>>>(rows, cols, vals,
                                                                row_ptr, rank, epack);

    init_ego<<<(N_TOT * DIM / 4 + 255) / 256, 256, 0, stream>>>(ue, ie, ego, out);

    for (int k = 0; k < 3; ++k) {
        spmm_gather<<<(N_TOT + 3) / 4, 256, 0, stream>>>(row_ptr, epack, ego, side);
        transform_gemm<<<(N_TOT + 63) / 64, 256, 0, stream>>>(Wg[k], bg[k], Wb[k], bb[k],
                                                              side, ego, out, k);
    }
}

// Round 5
// 809.037 us; speedup vs baseline: 1.0674x; 1.0674x over previous
//
#include <hip/hip_runtime.h>

#define N_TOT      150000
#define N_USER     50000
#define N_EDGE     2400000
#define DIM        64
#define OUT_STRIDE 256
#define SLOPE      0.2f
#define NB_SCAN    ((N_TOT + 255) / 256)   // 587

// ---- ws layout ----
// ego    : [N,64] fp32 (in-place across layers)
// side   : [N,64] fp32   (aliased as rank[E] during CSR build)
// epack  : [E] int2 (col, val_bits)
// row_ptr: [N+1] int
// cnt    : [N] int (histogram counts)
// bsum   : [NB_SCAN] int

__global__ void init_ego(const float* __restrict__ ue, const float* __restrict__ ie,
                         float* __restrict__ ego, float* __restrict__ out) {
    int idx = blockIdx.x * blockDim.x + threadIdx.x;          // float4 index
    if (idx >= N_TOT * DIM / 4) return;
    int n  = idx >> 4;
    int c4 = idx & 15;
    float4 v = (n < N_USER) ? ((const float4*)ue)[idx]
                            : ((const float4*)ie)[idx - N_USER * (DIM / 4)];
    ((float4*)ego)[idx] = v;
    ((float4*)out)[n * (OUT_STRIDE / 4) + c4] = v;
}

// Histogram + per-edge rank in ONE pass: the atomic return value IS the rank.
// 4 edges per thread (int4 reads). Measured stable at ~100 us (LLC atomic
// throughput bound; neither 4->8 ILP nor occupancy moves it).
__global__ void hist_rank(const int* __restrict__ rows, int* __restrict__ cnt,
                          int* __restrict__ rank) {
    int t = blockIdx.x * blockDim.x + threadIdx.x;
    if (t >= N_EDGE / 4) return;
    int4 r4 = ((const int4*)rows)[t];
    int4 k4;
    k4.x = atomicAdd(&cnt[r4.x], 1);
    k4.y = atomicAdd(&cnt[r4.y], 1);
    k4.z = atomicAdd(&cnt[r4.z], 1);
    k4.w = atomicAdd(&cnt[r4.w], 1);
    ((int4*)rank)[t] = k4;
}

// Hierarchical scan, stage 1: per-256-chunk exclusive scan + block totals.
__global__ __launch_bounds__(256) void scan_partial(const int* __restrict__ cnt,
                                                    int* __restrict__ row_ptr,
                                                    int* __restrict__ bsum) {
    __shared__ int s[256];
    int tid = threadIdx.x;
    int i = blockIdx.x * 256 + tid;
    int v = (i < N_TOT) ? cnt[i] : 0;
    s[tid] = v;
    __syncthreads();
    for (int off = 1; off < 256; off <<= 1) {                 // Hillis-Steele inclusive
        int t = (tid >= off) ? s[tid - off] : 0;
        __syncthreads();
        s[tid] += t;
        __syncthreads();
    }
    if (i < N_TOT) row_ptr[i] = s[tid] - v;                   // local exclusive
    if (tid == 255) bsum[blockIdx.x] = s[255];
}

// Stage 2: single block scans the NB_SCAN block totals (exclusive, in place).
__global__ __launch_bounds__(1024) void scan_bsums(int* __restrict__ bsum) {
    __shared__ int s[1024];
    int tid = threadIdx.x;
    int v = (tid < NB_SCAN) ? bsum[tid] : 0;
    s[tid] = v;
    __syncthreads();
    for (int off = 1; off < 1024; off <<= 1) {
        int t = (tid >= off) ? s[tid - off] : 0;
        __syncthreads();
        s[tid] += t;
        __syncthreads();
    }
    if (tid < NB_SCAN) bsum[tid] = s[tid] - v;
}

// Stage 3: add block offsets; write final row_ptr.
__global__ __launch_bounds__(256) void add_offsets(int* __restrict__ row_ptr,
                                                   const int* __restrict__ bsum) {
    int i = blockIdx.x * 256 + threadIdx.x;
    if (i < N_TOT) row_ptr[i] += bsum[blockIdx.x];
    if (i == 0) row_ptr[N_TOT] = N_EDGE;
}

// Atomic-free scatter: pos = row_ptr[row] + rank (deterministic). Pure
// streaming reads + one random 8B write per edge. 4 edges/thread for MLP.
__global__ void scatter_edges(const int* __restrict__ rows, const int* __restrict__ cols,
                              const float* __restrict__ vals,
                              const int* __restrict__ row_ptr,
                              const int* __restrict__ rank, int2* __restrict__ epack) {
    int t = blockIdx.x * blockDim.x + threadIdx.x;
    if (t >= N_EDGE / 4) return;
    int4   r4 = ((const int4*)rows)[t];
    int4   k4 = ((const int4*)rank)[t];
    int4   c4 = ((const int4*)cols)[t];
    float4 v4 = ((const float4*)vals)[t];
    epack[row_ptr[r4.x] + k4.x] = make_int2(c4.x, __float_as_int(v4.x));
    epack[row_ptr[r4.y] + k4.y] = make_int2(c4.y, __float_as_int(v4.y));
    epack[row_ptr[r4.z] + k4.z] = make_int2(c4.z, __float_as_int(v4.z));
    epack[row_ptr[r4.w] + k4.w] = make_int2(c4.w, __float_as_int(v4.w));
}

// side = A @ ego (CSR gather). One wave per row; 4 edge-groups x 16 lanes,
// float4 per lane. 16-edge head (measured-best round 3; 32-edge regressed).
// Per-group edge order identical across variants -> bitwise-identical sum.
__global__ __launch_bounds__(256) void spmm_gather(
    const int* __restrict__ row_ptr, const int2* __restrict__ epack,
    const float* __restrict__ ego, float* __restrict__ side) {
    int lane = threadIdx.x & 63;
    int row  = blockIdx.x * 4 + (threadIdx.x >> 6);
    if (row >= N_TOT) return;
    int beg = row_ptr[row];
    int end = row_ptr[row + 1];
    int g = lane >> 4;          // edge sub-group 0..3
    int q = lane & 15;          // dim quarter: dims q*4 .. q*4+3
    float4 acc = make_float4(0.f, 0.f, 0.f, 0.f);
    int i = beg;
    for (; i + 16 <= end; i += 16) {
        int4 e0 = ((const int4*)(epack + i))[g];              // edges i+2g, i+2g+1
        int4 e1 = ((const int4*)(epack + i + 8))[g];          // edges i+8+2g, i+8+2g+1
        float4 va = ((const float4*)(ego + (size_t)e0.x * DIM))[q];
        float4 vb = ((const float4*)(ego + (size_t)e0.z * DIM))[q];
        float4 vc = ((const float4*)(ego + (size_t)e1.x * DIM))[q];
        float4 vd = ((const float4*)(ego + (size_t)e1.z * DIM))[q];
        float wa = __int_as_float(e0.y);
        float wb = __int_as_float(e0.w);
        float wc = __int_as_float(e1.y);
        float wd = __int_as_float(e1.w);
        acc.x = fmaf(wa, va.x, acc.x); acc.y = fmaf(wa, va.y, acc.y);
        acc.z = fmaf(wa, va.z, acc.z); acc.w = fmaf(wa, va.w, acc.w);
        acc.x = fmaf(wb, vb.x, acc.x); acc.y = fmaf(wb, vb.y, acc.y);
        acc.z = fmaf(wb, vb.z, acc.z); acc.w = fmaf(wb, vb.w, acc.w);
        acc.x = fmaf(wc, vc.x, acc.x); acc.y = fmaf(wc, vc.y, acc.y);
        acc.z = fmaf(wc, vc.z, acc.z); acc.w = fmaf(wc, vc.w, acc.w);
        acc.x = fmaf(wd, vd.x, acc.x); acc.y = fmaf(wd, vd.y, acc.y);
        acc.z = fmaf(wd, vd.z, acc.z); acc.w = fmaf(wd, vd.w, acc.w);
    }
    for (; i + 8 <= end; i += 8) {
        int4 ee = ((const int4*)(epack + i))[g];
        float4 va = ((const float4*)(ego + (size_t)ee.x * DIM))[q];
        float4 vb = ((const float4*)(ego + (size_t)ee.z * DIM))[q];
        float wa = __int_as_float(ee.y);
        float wb = __int_as_float(ee.w);
        acc.x = fmaf(wa, va.x, acc.x); acc.y = fmaf(wa, va.y, acc.y);
        acc.z = fmaf(wa, va.z, acc.z); acc.w = fmaf(wa, va.w, acc.w);
        acc.x = fmaf(wb, vb.x, acc.x); acc.y = fmaf(wb, vb.y, acc.y);
        acc.z = fmaf(wb, vb.z, acc.z); acc.w = fmaf(wb, vb.w, acc.w);
    }
    for (; i < end; i += 4) {                                 // tail: <=7 edges
        if (i + g < end) {
            int2 e = epack[i + g];
            float4 v = ((const float4*)(ego + (size_t)e.x * DIM))[q];
            float w = __int_as_float(e.y);
            acc.x = fmaf(w, v.x, acc.x); acc.y = fmaf(w, v.y, acc.y);
            acc.z = fmaf(w, v.z, acc.z); acc.w = fmaf(w, v.w, acc.w);
        }
    }
    // combine the 4 edge-groups (lane bits 4 and 5)
    acc.x += __shfl_xor(acc.x, 16, 64); acc.y += __shfl_xor(acc.y, 16, 64);
    acc.z += __shfl_xor(acc.z, 16, 64); acc.w += __shfl_xor(acc.w, 16, 64);
    acc.x += __shfl_xor(acc.x, 32, 64); acc.y += __shfl_xor(acc.y, 32, 64);
    acc.z += __shfl_xor(acc.z, 32, 64); acc.w += __shfl_xor(acc.w, 32, 64);
    if (g == 0)
        *(float4*)(side + (size_t)row * DIM + q * 4) = acc;
}

// Dual 64x64 GEMM + LeakyReLU + add + l2norm per 64-row tile.
// v5: (a) register-transpose staging -> aligned b128 LDS stores, evenly
// spread over bank-groups (kills the 8-way scalar-store conflicts);
// (b) W read directly from global (L1/L2-resident 32 KB) -> LDS halved to
// 34.8 KB -> 4 blocks/CU (16 waves). FMA order/operands identical to the
// round-1/3 staged version -> bitwise-identical output.
__global__ __launch_bounds__(256, 4) void transform_gemm(
    const float* __restrict__ Wg, const float* __restrict__ bgv,
    const float* __restrict__ Wb, const float* __restrict__ bbv,
    const float* __restrict__ side, float* __restrict__ ego,
    float* __restrict__ out, int layer) {
    __shared__ float sST[DIM][68];     // sST[k][r] = side[R0+r][k]
    __shared__ float sPT[DIM][68];     // sPT[k][r] = (ego*side)[R0+r][k]
    int tid = threadIdx.x;
    int R0  = blockIdx.x * 64;

    // ---- staging: thread (rr,kk) owns rows 4rr..4rr+3, k-quarter 4kk..4kk+3
    {
        int kk = tid & 15, rr = tid >> 4;
        int k0s = kk * 4, r0s = rr * 4;
        float4 s0, s1, s2, s3, e0, e1, e2, e3;
        s0 = s1 = s2 = s3 = make_float4(0.f, 0.f, 0.f, 0.f);
        e0 = e1 = e2 = e3 = make_float4(0.f, 0.f, 0.f, 0.f);
        int row = R0 + r0s;
        if (row + 0 < N_TOT) {
            s0 = *(const float4*)&side[(size_t)(row + 0) * DIM + k0s];
            e0 = *(const float4*)&ego [(size_t)(row + 0) * DIM + k0s];
        }
        if (row + 1 < N_TOT) {
            s1 = *(const float4*)&side[(size_t)(row + 1) * DIM + k0s];
            e1 = *(const float4*)&ego [(size_t)(row + 1) * DIM + k0s];
        }
        if (row + 2 < N_TOT) {
            s2 = *(const float4*)&side[(size_t)(row + 2) * DIM + k0s];
            e2 = *(const float4*)&ego [(size_t)(row + 2) * DIM + k0s];
        }
        if (row + 3 < N_TOT) {
            s3 = *(const float4*)&side[(size_t)(row + 3) * DIM + k0s];
            e3 = *(const float4*)&ego [(size_t)(row + 3) * DIM + k0s];
        }
        float4 p0 = make_float4(s0.x * e0.x, s0.y * e0.y, s0.z * e0.z, s0.w * e0.w);
        float4 p1 = make_float4(s1.x * e1.x, s1.y * e1.y, s1.z * e1.z, s1.w * e1.w);
        float4 p2 = make_float4(s2.x * e2.x, s2.y * e2.y, s2.z * e2.z, s2.w * e2.w);
        float4 p3 = make_float4(s3.x * e3.x, s3.y * e3.y, s3.z * e3.z, s3.w * e3.w);
        // 4x4 register transpose, aligned float4 stores
        *(float4*)&sST[k0s + 0][r0s] = make_float4(s0.x, s1.x, s2.x, s3.x);
        *(float4*)&sST[k0s + 1][r0s] = make_float4(s0.y, s1.y, s2.y, s3.y);
        *(float4*)&sST[k0s + 2][r0s] = make_float4(s0.z, s1.z, s2.z, s3.z);
        *(float4*)&sST[k0s + 3][r0s] = make_float4(s0.w, s1.w, s2.w, s3.w);
        *(float4*)&sPT[k0s + 0][r0s] = make_float4(p0.x, p1.x, p2.x, p3.x);
        *(float4*)&sPT[k0s + 1][r0s] = make_float4(p0.y, p1.y, p2.y, p3.y);
        *(float4*)&sPT[k0s + 2][r0s] = make_float4(p0.z, p1.z, p2.z, p3.z);
        *(float4*)&sPT[k0s + 3][r0s] = make_float4(p0.w, p1.w, p2.w, p3.w);
    }
    __syncthreads();

    int tx = tid & 15, ty = tid >> 4;
    int c0 = tx * 4, r0 = ty * 4;
    const float4* Wg4 = (const float4*)Wg;     // row k, col-quad tx -> [k*16+tx]
    const float4* Wb4 = (const float4*)Wb;
    float ag[4][4] = {{0.f}}, ab[4][4] = {{0.f}};
    #pragma unroll 4
    for (int k = 0; k < DIM; ++k) {
        float4 s4 = *(const float4*)&sST[k][r0];
        float4 p4 = *(const float4*)&sPT[k][r0];
        float4 g4 = Wg4[k * 16 + tx];
        float4 b4 = Wb4[k * 16 + tx];
        float ss[4] = {s4.x, s4.y, s4.z, s4.w};
        float pp[4] = {p4.x, p4.y, p4.z, p4.w};
        float gg[4] = {g4.x, g4.y, g4.z, g4.w};
        float bw[4] = {b4.x, b4.y, b4.z, b4.w};
        #pragma unroll
        for (int i = 0; i < 4; ++i)
            #pragma unroll
            for (int j = 0; j < 4; ++j) {
                ag[i][j] = fmaf(ss[i], gg[j], ag[i][j]);
                ab[i][j] = fmaf(pp[i], bw[j], ab[i][j]);
            }
    }

    float4 bg4 = *(const float4*)&bgv[c0];
    float4 bb4 = *(const float4*)&bbv[c0];
    float bgl[4] = {bg4.x, bg4.y, bg4.z, bg4.w};
    float bbl[4] = {bb4.x, bb4.y, bb4.z, bb4.w};

    float ne[4][4];
    float ss2[4];
    #pragma unroll
    for (int i = 0; i < 4; ++i) {
        float s = 0.f;
        #pragma unroll
        for (int j = 0; j < 4; ++j) {
            float g = ag[i][j] + bgl[j];
            float b = ab[i][j] + bbl[j];
            g = g > 0.f ? g : SLOPE * g;
            b = b > 0.f ? b : SLOPE * b;
            float v = g + b;
            ne[i][j] = v;
            s = fmaf(v, v, s);
        }
        ss2[i] = s;
    }
    #pragma unroll
    for (int m = 1; m < 16; m <<= 1) {                        // reduce across tx group
        #pragma unroll
        for (int i = 0; i < 4; ++i) ss2[i] += __shfl_xor(ss2[i], m, 64);
    }

    float* outbase = out + (size_t)(layer + 1) * DIM;
    #pragma unroll
    for (int i = 0; i < 4; ++i) {
        int row = R0 + r0 + i;
        if (row >= N_TOT) break;
        float inv = 1.f / fmaxf(sqrtf(ss2[i]), 1e-12f);
        float4 e4 = make_float4(ne[i][0], ne[i][1], ne[i][2], ne[i][3]);
        float4 o4 = make_float4(ne[i][0] * inv, ne[i][1] * inv, ne[i][2] * inv, ne[i][3] * inv);
        *(float4*)&ego[(size_t)row * DIM + c0] = e4;
        *(float4*)&outbase[(size_t)row * OUT_STRIDE + c0] = o4;
    }
}

extern "C" void kernel_launch(void* const* d_in, const int* in_sizes, int n_in,
                              void* d_out, int out_size, void* d_ws, size_t ws_size,
                              hipStream_t stream) {
    const float* ue = (const float*)d_in[0];
    const float* ie = (const float*)d_in[1];
    const float* Wg[3] = {(const float*)d_in[2], (const float*)d_in[6], (const float*)d_in[10]};
    const float* bg[3] = {(const float*)d_in[3], (const float*)d_in[7], (const float*)d_in[11]};
    const float* Wb[3] = {(const float*)d_in[4], (const float*)d_in[8], (const float*)d_in[12]};
    const float* bb[3] = {(const float*)d_in[5], (const float*)d_in[9], (const float*)d_in[13]};
    const float* vals = (const float*)d_in[14];
    const int*  rows  = (const int*)d_in[15];
    const int*  cols  = (const int*)d_in[16];
    float* out = (float*)d_out;

    float* ego     = (float*)d_ws;
    float* side    = ego + (size_t)N_TOT * DIM;
    int2*  epack   = (int2*)(side + (size_t)N_TOT * DIM);
    int*   row_ptr = (int*)(epack + N_EDGE);
    int*   cnt     = row_ptr + (N_TOT + 16);
    int*   bsum    = cnt + N_TOT;
    int*   rank    = (int*)side;      // alias: side unused until layer loop

    // CSR build (adj constant across layers)
    hipMemsetAsync(cnt, 0, (size_t)N_TOT * sizeof(int), stream);
    hist_rank<<<(N_EDGE / 4 + 255) / 256, 256, 0, stream>>>(rows, cnt, rank);
    scan_partial<<<NB_SCAN, 256, 0, stream>>>(cnt, row_ptr, bsum);
    scan_bsums<<<1, 1024, 0, stream>>>(bsum);
    add_offsets<<<NB_SCAN, 256, 0, stream>>>(row_ptr, bsum);
    scatter_edges<<<(N_EDGE / 4 + 255) / 256, 256, 0, stream>>>(rows, cols, vals,
                                                                row_ptr, rank, epack);

    init_ego<<<(N_TOT * DIM / 4 + 255) / 256, 256, 0, stream>>>(ue, ie, ego, out);

    for (int k = 0; k < 3; ++k) {
        spmm_gather<<<(N_TOT + 3) / 4, 256, 0, stream>>>(row_ptr, epack, ego, side);
        transform_gemm<<<(N_TOT + 63) / 64, 256, 0, stream>>>(Wg[k], bg[k], Wb[k], bb[k],
                                                              side, ego, out, k);
    }
}

// Round 7
// 805.787 us; speedup vs baseline: 1.0717x; 1.0040x over previous
//
#include <hip/hip_runtime.h>

#define N_TOT      150000
#define N_USER     50000
#define N_EDGE     2400000
#define DIM        64
#define OUT_STRIDE 256
#define SLOPE      0.2f
#define NB_SCAN    ((N_TOT + 255) / 256)   // 587
#define NREP       8                       // one cnt replica per XCD class

// ---- ws layout ----
// ego    : [N,64] fp32 (in-place across layers)
// side   : [N,64] fp32   (aliased as rank[E] during CSR build)
// epack  : [E] int2 (col, val_bits)
// row_ptr: [N+1] int
// cntR   : [8][N] int (per-XCD-class histogram replicas -> scatter offsets)
// bsum   : [NB_SCAN] int

__global__ void init_ego(const float* __restrict__ ue, const float* __restrict__ ie,
                         float* __restrict__ ego, float* __restrict__ out) {
    int idx = blockIdx.x * blockDim.x + threadIdx.x;          // float4 index
    if (idx >= N_TOT * DIM / 4) return;
    int n  = idx >> 4;
    int c4 = idx & 15;
    float4 v = (n < N_USER) ? ((const float4*)ue)[idx]
                            : ((const float4*)ie)[idx - N_USER * (DIM / 4)];
    ((float4*)ego)[idx] = v;
    ((float4*)out)[n * (OUT_STRIDE / 4) + c4] = v;
}

// Histogram + per-edge rank, XCD-replicated: blocks of class (blockIdx&7)
// atomic into their own cnt replica. With round-robin block->XCD dispatch,
// replica lines stay in ONE XCD's L2 -> no cross-XCD line migration (the
// 75 MB of cnt writebacks seen in rounds 1-5). Rank = within-replica rank.
__global__ void hist_rank(const int* __restrict__ rows, int* __restrict__ cntR,
                          int* __restrict__ rank) {
    int t = blockIdx.x * blockDim.x + threadIdx.x;
    if (t >= N_EDGE / 4) return;
    int* cnt = cntR + (size_t)(blockIdx.x & (NREP - 1)) * N_TOT;
    int4 r4 = ((const int4*)rows)[t];
    int4 k4;
    k4.x = atomicAdd(&cnt[r4.x], 1);
    k4.y = atomicAdd(&cnt[r4.y], 1);
    k4.z = atomicAdd(&cnt[r4.z], 1);
    k4.w = atomicAdd(&cnt[r4.w], 1);
    ((int4*)rank)[t] = k4;
}

// Hierarchical scan, stage 1: per-256-chunk exclusive scan + block totals.
// Row count = sum over the 8 replicas (coalesced reads).
__global__ __launch_bounds__(256) void scan_partial(const int* __restrict__ cntR,
                                                    int* __restrict__ row_ptr,
                                                    int* __restrict__ bsum) {
    __shared__ int s[256];
    int tid = threadIdx.x;
    int i = blockIdx.x * 256 + tid;
    int v = 0;
    if (i < N_TOT) {
        #pragma unroll
        for (int x = 0; x < NREP; ++x) v += cntR[(size_t)x * N_TOT + i];
    }
    s[tid] = v;
    __syncthreads();
    for (int off = 1; off < 256; off <<= 1) {                 // Hillis-Steele inclusive
        int t = (tid >= off) ? s[tid - off] : 0;
        __syncthreads();
        s[tid] += t;
        __syncthreads();
    }
    if (i < N_TOT) row_ptr[i] = s[tid] - v;                   // local exclusive
    if (tid == 255) bsum[blockIdx.x] = s[255];
}

// Stage 2: single block scans the NB_SCAN block totals (exclusive, in place).
__global__ __launch_bounds__(1024) void scan_bsums(int* __restrict__ bsum) {
    __shared__ int s[1024];
    int tid = threadIdx.x;
    int v = (tid < NB_SCAN) ? bsum[tid] : 0;
    s[tid] = v;
    __syncthreads();
    for (int off = 1; off < 1024; off <<= 1) {
        int t = (tid >= off) ? s[tid - off] : 0;
        __syncthreads();
        s[tid] += t;
        __syncthreads();
    }
    if (tid < NB_SCAN) bsum[tid] = s[tid] - v;
}

// Stage 3: add block offsets; write final row_ptr.
__global__ __launch_bounds__(256) void add_offsets(int* __restrict__ row_ptr,
                                                   const int* __restrict__ bsum) {
    int i = blockIdx.x * 256 + threadIdx.x;
    if (i < N_TOT) row_ptr[i] += bsum[blockIdx.x];
    if (i == 0) row_ptr[N_TOT] = N_EDGE;
}

// Stage 4: per-row prefix over replicas, in place:
// cntR[x][row] <- row_ptr[row] + sum_{y<x} cntR[y][row]   (scatter base)
// Each x-iteration is a fully coalesced read+write sweep.
__global__ __launch_bounds__(256) void replica_prefix(const int* __restrict__ row_ptr,
                                                      int* __restrict__ cntR) {
    int i = blockIdx.x * 256 + threadIdx.x;
    if (i >= N_TOT) return;
    int run = row_ptr[i];
    #pragma unroll
    for (int x = 0; x < NREP; ++x) {
        int t = cntR[(size_t)x * N_TOT + i];
        cntR[(size_t)x * N_TOT + i] = run;
        run += t;
    }
}

// Atomic-free scatter: pos = off[class][row] + rank. class = blockIdx&7 is
// deterministic and identical to hist_rank's (same grid shape, 4 edges/thread,
// edges never cross a block boundary). 4 edges/thread for random-write MLP.
__global__ void scatter_edges(const int* __restrict__ rows, const int* __restrict__ cols,
                              const float* __restrict__ vals,
                              const int* __restrict__ offR,
                              const int* __restrict__ rank, int2* __restrict__ epack) {
    int t = blockIdx.x * blockDim.x + threadIdx.x;
    if (t >= N_EDGE / 4) return;
    const int* off = offR + (size_t)(blockIdx.x & (NREP - 1)) * N_TOT;
    int4   r4 = ((const int4*)rows)[t];
    int4   k4 = ((const int4*)rank)[t];
    int4   c4 = ((const int4*)cols)[t];
    float4 v4 = ((const float4*)vals)[t];
    epack[off[r4.x] + k4.x] = make_int2(c4.x, __float_as_int(v4.x));
    epack[off[r4.y] + k4.y] = make_int2(c4.y, __float_as_int(v4.y));
    epack[off[r4.z] + k4.z] = make_int2(c4.z, __float_as_int(v4.z));
    epack[off[r4.w] + k4.w] = make_int2(c4.w, __float_as_int(v4.w));
}

// side = A @ ego (CSR gather). One wave per row; 4 edge-groups x 16 lanes,
// float4 per lane. 16-edge head (measured-best round 3; 32-edge regressed).
__global__ __launch_bounds__(256) void spmm_gather(
    const int* __restrict__ row_ptr, const int2* __restrict__ epack,
    const float* __restrict__ ego, float* __restrict__ side) {
    int lane = threadIdx.x & 63;
    int row  = blockIdx.x * 4 + (threadIdx.x >> 6);
    if (row >= N_TOT) return;
    int beg = row_ptr[row];
    int end = row_ptr[row + 1];
    int g = lane >> 4;          // edge sub-group 0..3
    int q = lane & 15;          // dim quarter: dims q*4 .. q*4+3
    float4 acc = make_float4(0.f, 0.f, 0.f, 0.f);
    int i = beg;
    for (; i + 16 <= end; i += 16) {
        int4 e0 = ((const int4*)(epack + i))[g];              // edges i+2g, i+2g+1
        int4 e1 = ((const int4*)(epack + i + 8))[g];          // edges i+8+2g, i+8+2g+1
        float4 va = ((const float4*)(ego + (size_t)e0.x * DIM))[q];
        float4 vb = ((const float4*)(ego + (size_t)e0.z * DIM))[q];
        float4 vc = ((const float4*)(ego + (size_t)e1.x * DIM))[q];
        float4 vd = ((const float4*)(ego + (size_t)e1.z * DIM))[q];
        float wa = __int_as_float(e0.y);
        float wb = __int_as_float(e0.w);
        float wc = __int_as_float(e1.y);
        float wd = __int_as_float(e1.w);
        acc.x = fmaf(wa, va.x, acc.x); acc.y = fmaf(wa, va.y, acc.y);
        acc.z = fmaf(wa, va.z, acc.z); acc.w = fmaf(wa, va.w, acc.w);
        acc.x = fmaf(wb, vb.x, acc.x); acc.y = fmaf(wb, vb.y, acc.y);
        acc.z = fmaf(wb, vb.z, acc.z); acc.w = fmaf(wb, vb.w, acc.w);
        acc.x = fmaf(wc, vc.x, acc.x); acc.y = fmaf(wc, vc.y, acc.y);
        acc.z = fmaf(wc, vc.z, acc.z); acc.w = fmaf(wc, vc.w, acc.w);
        acc.x = fmaf(wd, vd.x, acc.x); acc.y = fmaf(wd, vd.y, acc.y);
        acc.z = fmaf(wd, vd.z, acc.z); acc.w = fmaf(wd, vd.w, acc.w);
    }
    for (; i + 8 <= end; i += 8) {
        int4 ee = ((const int4*)(epack + i))[g];
        float4 va = ((const float4*)(ego + (size_t)ee.x * DIM))[q];
        float4 vb = ((const float4*)(ego + (size_t)ee.z * DIM))[q];
        float wa = __int_as_float(ee.y);
        float wb = __int_as_float(ee.w);
        acc.x = fmaf(wa, va.x, acc.x); acc.y = fmaf(wa, va.y, acc.y);
        acc.z = fmaf(wa, va.z, acc.z); acc.w = fmaf(wa, va.w, acc.w);
        acc.x = fmaf(wb, vb.x, acc.x); acc.y = fmaf(wb, vb.y, acc.y);
        acc.z = fmaf(wb, vb.z, acc.z); acc.w = fmaf(wb, vb.w, acc.w);
    }
    for (; i < end; i += 4) {                                 // tail: <=7 edges
        if (i + g < end) {
            int2 e = epack[i + g];
            float4 v = ((const float4*)(ego + (size_t)e.x * DIM))[q];
            float w = __int_as_float(e.y);
            acc.x = fmaf(w, v.x, acc.x); acc.y = fmaf(w, v.y, acc.y);
            acc.z = fmaf(w, v.z, acc.z); acc.w = fmaf(w, v.w, acc.w);
        }
    }
    // combine the 4 edge-groups (lane bits 4 and 5)
    acc.x += __shfl_xor(acc.x, 16, 64); acc.y += __shfl_xor(acc.y, 16, 64);
    acc.z += __shfl_xor(acc.z, 16, 64); acc.w += __shfl_xor(acc.w, 16, 64);
    acc.x += __shfl_xor(acc.x, 32, 64); acc.y += __shfl_xor(acc.y, 32, 64);
    acc.z += __shfl_xor(acc.z, 32, 64); acc.w += __shfl_xor(acc.w, 32, 64);
    if (g == 0)
        *(float4*)(side + (size_t)row * DIM + q * 4) = acc;
}

// Dual 64x64 GEMM + LeakyReLU + add + l2norm per 64-row tile.
// Round-3 measured-best form (scalar transposed staging + W in LDS);
// v5's reg-transpose/W-global variant measured slightly worse — reverted.
__global__ __launch_bounds__(256) void transform_gemm(
    const float* __restrict__ Wg, const float* __restrict__ bgv,
    const float* __restrict__ Wb, const float* __restrict__ bbv,
    const float* __restrict__ side, float* __restrict__ ego,
    float* __restrict__ out, int layer) {
    __shared__ float sST[DIM][68];     // sST[k][r] = side[R0+r][k]
    __shared__ float sPT[DIM][68];     // sPT[k][r] = (ego*side)[R0+r][k]
    __shared__ float sWg[DIM][DIM];
    __shared__ float sWb[DIM][DIM];
    int tid = threadIdx.x;
    int R0  = blockIdx.x * 64;

    #pragma unroll
    for (int it = 0; it < 4; ++it) {                          // stage W matrices
        int f = tid + it * 256;                               // float4 idx 0..1023
        float4 wg = ((const float4*)Wg)[f];
        float4 wb = ((const float4*)Wb)[f];
        int k = f >> 4, c = (f & 15) * 4;
        *(float4*)&sWg[k][c] = wg;
        *(float4*)&sWb[k][c] = wb;
    }
    #pragma unroll
    for (int it = 0; it < 4; ++it) {                          // stage side/p transposed
        int f  = tid + it * 256;
        int r  = f >> 4, k0 = (f & 15) * 4;
        int row = R0 + r;
        float4 s4 = make_float4(0.f, 0.f, 0.f, 0.f);
        float4 e4 = make_float4(0.f, 0.f, 0.f, 0.f);
        if (row < N_TOT) {
            s4 = *(const float4*)&side[(size_t)row * DIM + k0];
            e4 = *(const float4*)&ego [(size_t)row * DIM + k0];
        }
        sST[k0 + 0][r] = s4.x; sST[k0 + 1][r] = s4.y;
        sST[k0 + 2][r] = s4.z; sST[k0 + 3][r] = s4.w;
        sPT[k0 + 0][r] = s4.x * e4.x; sPT[k0 + 1][r] = s4.y * e4.y;
        sPT[k0 + 2][r] = s4.z * e4.z; sPT[k0 + 3][r] = s4.w * e4.w;
    }
    __syncthreads();

    int tx = tid & 15, ty = tid >> 4;
    int c0 = tx * 4, r0 = ty * 4;
    float ag[4][4] = {{0.f}}, ab[4][4] = {{0.f}};
    #pragma unroll 4
    for (int k = 0; k < DIM; ++k) {
        float4 s4 = *(const float4*)&sST[k][r0];
        float4 p4 = *(const float4*)&sPT[k][r0];
        float4 g4 = *(const float4*)&sWg[k][c0];
        float4 b4 = *(const float4*)&sWb[k][c0];
        float ss[4] = {s4.x, s4.y, s4.z, s4.w};
        float pp[4] = {p4.x, p4.y, p4.z, p4.w};
        float gg[4] = {g4.x, g4.y, g4.z, g4.w};
        float bw[4] = {b4.x, b4.y, b4.z, b4.w};
        #pragma unroll
        for (int i = 0; i < 4; ++i)
            #pragma unroll
            for (int j = 0; j < 4; ++j) {
                ag[i][j] = fmaf(ss[i], gg[j], ag[i][j]);
                ab[i][j] = fmaf(pp[i], bw[j], ab[i][j]);
            }
    }

    float4 bg4 = *(const float4*)&bgv[c0];
    float4 bb4 = *(const float4*)&bbv[c0];
    float bgl[4] = {bg4.x, bg4.y, bg4.z, bg4.w};
    float bbl[4] = {bb4.x, bb4.y, bb4.z, bb4.w};

    float ne[4][4];
    float ss2[4];
    #pragma unroll
    for (int i = 0; i < 4; ++i) {
        float s = 0.f;
        #pragma unroll
        for (int j = 0; j < 4; ++j) {
            float g = ag[i][j] + bgl[j];
            float b = ab[i][j] + bbl[j];
            g = g > 0.f ? g : SLOPE * g;
            b = b > 0.f ? b : SLOPE * b;
            float v = g + b;
            ne[i][j] = v;
            s = fmaf(v, v, s);
        }
        ss2[i] = s;
    }
    #pragma unroll
    for (int m = 1; m < 16; m <<= 1) {                        // reduce across tx group
        #pragma unroll
        for (int i = 0; i < 4; ++i) ss2[i] += __shfl_xor(ss2[i], m, 64);
    }

    float* outbase = out + (size_t)(layer + 1) * DIM;
    #pragma unroll
    for (int i = 0; i < 4; ++i) {
        int row = R0 + r0 + i;
        if (row >= N_TOT) break;
        float inv = 1.f / fmaxf(sqrtf(ss2[i]), 1e-12f);
        float4 e4 = make_float4(ne[i][0], ne[i][1], ne[i][2], ne[i][3]);
        float4 o4 = make_float4(ne[i][0] * inv, ne[i][1] * inv, ne[i][2] * inv, ne[i][3] * inv);
        *(float4*)&ego[(size_t)row * DIM + c0] = e4;
        *(float4*)&outbase[(size_t)row * OUT_STRIDE + c0] = o4;
    }
}

extern "C" void kernel_launch(void* const* d_in, const int* in_sizes, int n_in,
                              void* d_out, int out_size, void* d_ws, size_t ws_size,
                              hipStream_t stream) {
    const float* ue = (const float*)d_in[0];
    const float* ie = (const float*)d_in[1];
    const float* Wg[3] = {(const float*)d_in[2], (const float*)d_in[6], (const float*)d_in[10]};
    const float* bg[3] = {(const float*)d_in[3], (const float*)d_in[7], (const float*)d_in[11]};
    const float* Wb[3] = {(const float*)d_in[4], (const float*)d_in[8], (const float*)d_in[12]};
    const float* bb[3] = {(const float*)d_in[5], (const float*)d_in[9], (const float*)d_in[13]};
    const float* vals = (const float*)d_in[14];
    const int*  rows  = (const int*)d_in[15];
    const int*  cols  = (const int*)d_in[16];
    float* out = (float*)d_out;

    float* ego     = (float*)d_ws;
    float* side    = ego + (size_t)N_TOT * DIM;
    int2*  epack   = (int2*)(side + (size_t)N_TOT * DIM);
    int*   row_ptr = (int*)(epack + N_EDGE);
    int*   cntR    = row_ptr + (N_TOT + 16);
    int*   bsum    = cntR + (size_t)NREP * N_TOT;
    int*   rank    = (int*)side;      // alias: side unused until layer loop

    // CSR build (adj constant across layers)
    hipMemsetAsync(cntR, 0, (size_t)NREP * N_TOT * sizeof(int), stream);
    hist_rank<<<(N_EDGE / 4 + 255) / 256, 256, 0, stream>>>(rows, cntR, rank);
    scan_partial<<<NB_SCAN, 256, 0, stream>>>(cntR, row_ptr, bsum);
    scan_bsums<<<1, 1024, 0, stream>>>(bsum);
    add_offsets<<<NB_SCAN, 256, 0, stream>>>(row_ptr, bsum);
    replica_prefix<<<NB_SCAN, 256, 0, stream>>>(row_ptr, cntR);
    scatter_edges<<<(N_EDGE / 4 + 255) / 256, 256, 0, stream>>>(rows, cols, vals,
                                                                cntR, rank, epack);

    init_ego<<<(N_TOT * DIM / 4 + 255) / 256, 256, 0, stream>>>(ue, ie, ego, out);

    for (int k = 0; k < 3; ++k) {
        spmm_gather<<<(N_TOT + 3) / 4, 256, 0, stream>>>(row_ptr, epack, ego, side);
        transform_gemm<<<(N_TOT + 63) / 64, 256, 0, stream>>>(Wg[k], bg[k], Wb[k], bb[k],
                                                              side, ego, out, k);
    }
}